// Round 11
// baseline (359.871 us; speedup 1.0000x reference)
//
#include <hip/hip_runtime.h>

typedef unsigned short ushort_t;
typedef unsigned int uint32;
typedef unsigned long long ull;
typedef __attribute__((ext_vector_type(8))) short short8;
typedef __attribute__((ext_vector_type(4))) float f32x4;
typedef __attribute__((ext_vector_type(2))) unsigned long long ull2;

#define LOG2E   1.4426950408889634f
#define LOG2E2  2.8853900817779268f
#define MFMA16  __builtin_amdgcn_mfma_f32_16x16x32_bf16

static __device__ __forceinline__ ushort_t f2bf(float f) {
    uint32 u = __float_as_uint(f);
    u += 0x7FFFu + ((u >> 16) & 1u);
    return (ushort_t)(u >> 16);
}
static __device__ __forceinline__ float rcp_(float x) { return __builtin_amdgcn_rcpf(x); }
static __device__ __forceinline__ float ex2_(float x) { return __builtin_amdgcn_exp2f(x); }
// sigmoid with pre-scaled arg (x already multiplied by log2e)
static __device__ __forceinline__ float sigp_(float x) { return rcp_(1.0f + ex2_(-x)); }

static __device__ __forceinline__ float gate_update(const f32x4 a, float& cc) {
    float i_ = sigp_(a[0]);
    float f_ = sigp_(a[1]);
    float g_ = fmaf(2.f, sigp_(a[2]), -1.f);
    float o_ = sigp_(a[3]);
    cc = fmaf(f_, cc, i_ * g_);
    return o_ * fmaf(2.f, sigp_(cc * LOG2E2), -1.f);
}
static __device__ __forceinline__ uint2 pack4(float a, float b, float c, float d) {
    uint2 r;
    asm("v_cvt_pk_bf16_f32 %0, %1, %2" : "=v"(r.x) : "v"(a), "v"(b));
    asm("v_cvt_pk_bf16_f32 %0, %1, %2" : "=v"(r.y) : "v"(c), "v"(d));
    return r;
}

// ---------------- prep (unchanged) ----------------
template<int LAYER>
__global__ void prep_frag(const float* __restrict__ Whh, const float* __restrict__ Wih,
                          ushort_t* __restrict__ wfrag) {
    constexpr int KT  = (LAYER == 0) ? 6 : 8;
    constexpr int DIN = (LAYER == 0) ? 64 : 128;
    int i = blockIdx.x * 256 + threadIdx.x;
    int e    = i & 7;
    int lane = (i >> 3) & 63;
    int r3   = i >> 9;
    int kt   = r3 % KT;
    int r4   = r3 / KT;
    int tq   = r4 & 3;
    int w    = r4 >> 2;
    if (w >= 8) return;
    int ml  = lane & 15;
    int kga = ml >> 2;
    int j   = ml & 3;
    int k   = kt * 32 + (lane >> 4) * 8 + e;
    int row = j * 128 + w * 16 + kga * 4 + tq;
    float scale = (j == 2) ? LOG2E2 : LOG2E;
    float v = (k < 128) ? Whh[row * 128 + k] : Wih[row * DIN + (k - 128)];
    wfrag[i] = f2bf(v * scale);
}

__global__ void prep_bias(const float* __restrict__ bih0, const float* __restrict__ bhh0,
                          const float* __restrict__ bih1, const float* __restrict__ bhh1,
                          float* __restrict__ bp0, float* __restrict__ bp1,
                          uint32* __restrict__ flags) {
    int i = blockIdx.x * 256 + threadIdx.x;   // 0..1023
    flags[i] = 0u;                            // reset pipeline flags (graph-replay safe)
    flags[i + 1024] = 0u;
    int p = i & 511;
    int w = p >> 6, tq = (p >> 4) & 3, kga = (p >> 2) & 3, j = p & 3;
    int row = j * 128 + w * 16 + kga * 4 + tq;
    float scale = (j == 2) ? LOG2E2 : LOG2E;
    if (i < 512) bp0[p] = (bih0[row] + bhh0[row]) * scale;
    else         bp1[p] = (bih1[row] + bhh1[row]) * scale;
}

// ---------------- M-role: h-chain MFMA + elementwise (critical path only) ------
template<int KT, bool IS_L0>
__device__ __forceinline__ void m_loop(const int blk, const ushort_t* __restrict__ wfrag,
                                       float* __restrict__ lastH,
                                       ushort_t* hb, float* accq)
{
    const int tid  = threadIdx.x;
    const int w    = tid >> 6;            // 0..3
    const int lane = tid & 63;
    const int n    = lane & 15;
    const int kg   = lane >> 4;
    const int foff = kg * 128 + n * 8;
    const int b0   = blk * 16;

    short8 wfh[2][4][4];
#pragma unroll
    for (int s = 0; s < 2; ++s)
#pragma unroll
        for (int tq = 0; tq < 4; ++tq)
#pragma unroll
            for (int kt = 0; kt < 4; ++kt)
                wfh[s][tq][kt] = *(const short8*)
                    &wfrag[((((2 * w + s) * 4 + tq) * KT + kt) * 64 + lane) * 8];

    float cc0[4] = {0, 0, 0, 0}, cc1[4] = {0, 0, 0, 0};
    const int hc0 = (2 * w) * 16 + kg * 4;
    const int hc1 = (2 * w + 1) * 16 + kg * 4;
    const int qa0 = hc0 * 64 + n * 4;
    const int qa1 = hc1 * 64 + n * 4;
    const int hw0 = ((hc0 >> 5) * 4 + ((hc0 >> 3) & 3)) * 128 + n * 8 + (hc0 & 7);
    const int hw1 = ((hc1 >> 5) * 4 + ((hc1 >> 3) & 3)) * 128 + n * 8 + (hc1 & 7);

    __syncthreads();   // V staged xb0/xb1
    __syncthreads();   // V wrote xacc[0] -> accq[0]

#define MSTEP(P, T)                                                                \
    {                                                                              \
        f32x4 a0[4], a1[4];                                                        \
        _Pragma("unroll")                                                          \
        for (int tq = 0; tq < 4; ++tq) {                                           \
            a0[tq] = *(const f32x4*)&accq[(P) * 8192 + qa0 + tq * 64];             \
            a1[tq] = *(const f32x4*)&accq[(P) * 8192 + qa1 + tq * 64];             \
        }                                                                          \
        short8 hfr[4];                                                             \
        _Pragma("unroll")                                                          \
        for (int kt = 0; kt < 4; ++kt)                                             \
            hfr[kt] = *(const short8*)&hb[(P) * 2048 + kt * 512 + foff];           \
        _Pragma("unroll")                                                          \
        for (int kt = 0; kt < 4; ++kt) {                                           \
            _Pragma("unroll")                                                      \
            for (int tq = 0; tq < 4; ++tq) {                                       \
                a0[tq] = MFMA16(wfh[0][tq][kt], hfr[kt], a0[tq], 0, 0, 0);         \
                a1[tq] = MFMA16(wfh[1][tq][kt], hfr[kt], a1[tq], 0, 0, 0);         \
            }                                                                      \
        }                                                                          \
        float hv00 = gate_update(a0[0], cc0[0]);                                   \
        float hv01 = gate_update(a0[1], cc0[1]);                                   \
        float hv02 = gate_update(a0[2], cc0[2]);                                   \
        float hv03 = gate_update(a0[3], cc0[3]);                                   \
        float hv10 = gate_update(a1[0], cc1[0]);                                   \
        float hv11 = gate_update(a1[1], cc1[1]);                                   \
        float hv12 = gate_update(a1[2], cc1[2]);                                   \
        float hv13 = gate_update(a1[3], cc1[3]);                                   \
        uint2 q0 = pack4(hv00, hv01, hv02, hv03);                                  \
        uint2 q1 = pack4(hv10, hv11, hv12, hv13);                                  \
        *(uint2*)&hb[((P) ^ 1) * 2048 + hw0] = q0;                                 \
        *(uint2*)&hb[((P) ^ 1) * 2048 + hw1] = q1;                                 \
        if (!IS_L0 && (T) == 255) {                                                \
            f32x4 o0 = {hv00, hv01, hv02, hv03};                                   \
            f32x4 o1 = {hv10, hv11, hv12, hv13};                                   \
            *(f32x4*)&lastH[(long)(b0 + n) * 128 + hc0] = o0;                      \
            *(f32x4*)&lastH[(long)(b0 + n) * 128 + hc1] = o1;                      \
        }                                                                          \
        __syncthreads();                                                           \
    }

#pragma unroll 1
    for (int t = 0; t < 256; t += 2) {
        MSTEP(0, t)
        MSTEP(1, t + 1)
    }
#undef MSTEP
}

// ---------------- V-role: xacc MFMA + all staging / record IO / flags ----------
// VSTEP order (round 11): global issues FIRST (record store; staged-reg LDS write
// frees regs; then staged global loads for T+3), xacc MFMAs LAST -> the pre-barrier
// vmcnt(0) drain finds the global ops already ~600+ cyc old.
// Record layout permuted for wave-contiguous 8-B ops: record = 512 ull;
// thread vtid owns ull [vtid] and [vtid+256] (store AND load sides match).
template<int KT, bool IS_L0>
__device__ __forceinline__ void v_loop(const int blk,
    const float* __restrict__ xin_f32, const uint32* __restrict__ xin_rec,
    const ushort_t* __restrict__ wfrag, const float* __restrict__ biasp,
    uint32* __restrict__ hrec, uint32* __restrict__ flagp,
    ushort_t* hb, ushort_t* xb, float* accq)
{
    constexpr int KX  = KT - 4;
    constexpr int XBS = KX * 512;         // ushorts per xb slot
    const int tid  = threadIdx.x;
    const int v    = (tid >> 6) - 4;      // 0..3
    const int lane = tid & 63;
    const int n    = lane & 15;
    const int kg   = lane >> 4;
    const int foff = kg * 128 + n * 8;
    const int vtid = tid - 256;           // 0..255
    const int b0   = blk * 16;

    short8 wfx[2][4][KX];
#pragma unroll
    for (int s = 0; s < 2; ++s)
#pragma unroll
        for (int tq = 0; tq < 4; ++tq)
#pragma unroll
            for (int kx = 0; kx < KX; ++kx)
                wfx[s][tq][kx] = *(const short8*)
                    &wfrag[((((2 * v + s) * 4 + tq) * KT + 4 + kx) * 64 + lane) * 8];
    f32x4 bias[2][4];
#pragma unroll
    for (int s = 0; s < 2; ++s)
#pragma unroll
        for (int tq = 0; tq < 4; ++tq)
            bias[s][tq] = *(const f32x4*)&biasp[(2 * v + s) * 64 + tq * 16 + kg * 4];

    const int hc0 = (2 * v) * 16 + kg * 4;
    const int hc1 = (2 * v + 1) * 16 + kg * 4;
    const int qa0 = hc0 * 64 + n * 4;
    const int qa1 = hc1 * 64 + n * 4;

    // staging maps
    const int skx = vtid >> 7;                       // L0: 0..1
    const int skg = (vtid >> 5) & 3;
    const int sn  = (vtid >> 1) & 15;
    const int se4 = (vtid & 1) * 4;
    const long xgbase = (long)(b0 + sn) * (256 * 64) + skx * 32 + skg * 8 + se4;
    const int  sxoff  = (skx * 4 + skg) * 128 + sn * 8 + se4;   // ushort idx
    const long rb     = (long)blk * (256 * 1024);               // u32 units
    ull*       stp    = (ull*)&hrec[rb];                        // record 0 base
    const ull* ldp    = (const ull*)&xin_rec[rb] + 3 * 512;     // record 3 base
    uint32 lastF = 0;
    uint2  xpack = {0u, 0u};
    ull    r64a = 0, r64b = 0;

    // prologue: stage x/rec[0]->xb0, [1]->xb1, [2]->regs (permuted record layout)
    if (IS_L0) {
        f32x4 x0 = *(const f32x4*)&xin_f32[xgbase];
        f32x4 x1 = *(const f32x4*)&xin_f32[xgbase + 64];
        f32x4 x2 = *(const f32x4*)&xin_f32[xgbase + 128];
        *(uint2*)&xb[0 * XBS + sxoff] = pack4(x0[0], x0[1], x0[2], x0[3]);
        *(uint2*)&xb[1 * XBS + sxoff] = pack4(x1[0], x1[1], x1[2], x1[3]);
        xpack = pack4(x2[0], x2[1], x2[2], x2[3]);
    } else {
        lastF = __hip_atomic_load(flagp, __ATOMIC_ACQUIRE, __HIP_MEMORY_SCOPE_AGENT);
        while (lastF < 4u) {
            __builtin_amdgcn_s_sleep(4);
            lastF = __hip_atomic_load(flagp, __ATOMIC_ACQUIRE, __HIP_MEMORY_SCOPE_AGENT);
        }
        const ull* p0 = (const ull*)&xin_rec[rb];
        ull a0_ = __hip_atomic_load(p0 + vtid,              __ATOMIC_RELAXED, __HIP_MEMORY_SCOPE_AGENT);
        ull a1_ = __hip_atomic_load(p0 + vtid + 256,        __ATOMIC_RELAXED, __HIP_MEMORY_SCOPE_AGENT);
        ull b0_ = __hip_atomic_load(p0 + 512 + vtid,        __ATOMIC_RELAXED, __HIP_MEMORY_SCOPE_AGENT);
        ull b1_ = __hip_atomic_load(p0 + 512 + vtid + 256,  __ATOMIC_RELAXED, __HIP_MEMORY_SCOPE_AGENT);
        r64a    = __hip_atomic_load(p0 + 1024 + vtid,       __ATOMIC_RELAXED, __HIP_MEMORY_SCOPE_AGENT);
        r64b    = __hip_atomic_load(p0 + 1024 + vtid + 256, __ATOMIC_RELAXED, __HIP_MEMORY_SCOPE_AGENT);
        ull2 w0; w0[0] = a0_; w0[1] = a1_;
        ull2 w1; w1[0] = b0_; w1[1] = b1_;
        *(ull2*)&xb[0 * XBS + vtid * 8] = w0;
        *(ull2*)&xb[1 * XBS + vtid * 8] = w1;
    }
    __syncthreads();   // xb0/xb1 visible

    // xacc[0] -> accq[0]
    {
        short8 xfr[KX];
#pragma unroll
        for (int kx = 0; kx < KX; ++kx)
            xfr[kx] = *(const short8*)&xb[0 * XBS + kx * 512 + foff];
#pragma unroll
        for (int tq = 0; tq < 4; ++tq) {
            f32x4 xa0 = bias[0][tq], xa1 = bias[1][tq];
#pragma unroll
            for (int kx = 0; kx < KX; ++kx) {
                xa0 = MFMA16(wfx[0][tq][kx], xfr[kx], xa0, 0, 0, 0);
                xa1 = MFMA16(wfx[1][tq][kx], xfr[kx], xa1, 0, 0, 0);
            }
            *(f32x4*)&accq[qa0 + tq * 64] = xa0;
            *(f32x4*)&accq[qa1 + tq * 64] = xa1;
        }
    }
    __syncthreads();   // accq[0] visible

#define VSTEP(P, T)                                                                \
    {                                                                              \
        /* (a) producer: record h[T-1] store — issued FIRST */                     \
        if (IS_L0 && (T) >= 1) {                                                   \
            ull2 rr = __builtin_bit_cast(ull2,                                     \
                          *(const short8*)&hb[(P) * 2048 + vtid * 8]);             \
            __hip_atomic_store(stp + vtid,       rr[0], __ATOMIC_RELAXED, __HIP_MEMORY_SCOPE_AGENT); \
            __hip_atomic_store(stp + vtid + 256, rr[1], __ATOMIC_RELAXED, __HIP_MEMORY_SCOPE_AGENT); \
            stp += 512;                                                            \
        }                                                                          \
        /* (b) write xb[P] from last step's staged regs (frees them) */            \
        if ((T) + 2 < 256) {                                                       \
            if (IS_L0) {                                                           \
                *(uint2*)&xb[(P) * XBS + sxoff] = xpack;                           \
            } else {                                                               \
                ull2 wv; wv[0] = r64a; wv[1] = r64b;                               \
                *(ull2*)&xb[(P) * XBS + vtid * 8] = wv;                            \
            }                                                                      \
        }                                                                          \
        /* (c) issue staged global loads for T+3 (consumed next step) */           \
        if ((T) + 3 < 256) {                                                       \
            if (IS_L0) {                                                           \
                f32x4 xv = *(const f32x4*)&xin_f32[xgbase + (long)((T) + 3) * 64]; \
                xpack = pack4(xv[0], xv[1], xv[2], xv[3]);                         \
            } else {                                                               \
                const uint32 want = (uint32)((T) + 4);                             \
                if (lastF < want) {                                                \
                    lastF = __hip_atomic_load(flagp, __ATOMIC_ACQUIRE, __HIP_MEMORY_SCOPE_AGENT); \
                    while (lastF < want) {                                         \
                        __builtin_amdgcn_s_sleep(4);                               \
                        lastF = __hip_atomic_load(flagp, __ATOMIC_ACQUIRE, __HIP_MEMORY_SCOPE_AGENT); \
                    }                                                              \
                }                                                                  \
                r64a = __hip_atomic_load(ldp + vtid,       __ATOMIC_RELAXED, __HIP_MEMORY_SCOPE_AGENT); \
                r64b = __hip_atomic_load(ldp + vtid + 256, __ATOMIC_RELAXED, __HIP_MEMORY_SCOPE_AGENT); \
                ldp += 512;                                                        \
            }                                                                      \
        }                                                                          \
        /* (d) xacc MFMAs — long block; global ops age while this runs */         \
        if ((T) < 255) {                                                           \
            short8 xfr[KX];                                                        \
            _Pragma("unroll")                                                      \
            for (int kx = 0; kx < KX; ++kx)                                        \
                xfr[kx] = *(const short8*)&xb[((P) ^ 1) * XBS + kx * 512 + foff];  \
            _Pragma("unroll")                                                      \
            for (int tq = 0; tq < 4; ++tq) {                                       \
                f32x4 xa0 = bias[0][tq], xa1 = bias[1][tq];                        \
                _Pragma("unroll")                                                  \
                for (int kx = 0; kx < KX; ++kx) {                                  \
                    xa0 = MFMA16(wfx[0][tq][kx], xfr[kx], xa0, 0, 0, 0);           \
                    xa1 = MFMA16(wfx[1][tq][kx], xfr[kx], xa1, 0, 0, 0);           \
                }                                                                  \
                *(f32x4*)&accq[((P) ^ 1) * 8192 + qa0 + tq * 64] = xa0;            \
                *(f32x4*)&accq[((P) ^ 1) * 8192 + qa1 + tq * 64] = xa1;            \
            }                                                                      \
        }                                                                          \
        __syncthreads();                                                           \
        if (IS_L0 && vtid == 0 && ((T) & 1) == 0 && (T) >= 2)                      \
            __hip_atomic_store(flagp, (uint32)(T), __ATOMIC_RELEASE, __HIP_MEMORY_SCOPE_AGENT); \
    }

#pragma unroll 1
    for (int t = 0; t < 256; t += 2) {
        VSTEP(0, t)
        VSTEP(1, t + 1)
    }
#undef VSTEP

    // record 255 (h[255] sits in hb parity 0)
    if (IS_L0) {
        ull2 rr = __builtin_bit_cast(ull2, *(const short8*)&hb[vtid * 8]);
        __hip_atomic_store(stp + vtid,       rr[0], __ATOMIC_RELAXED, __HIP_MEMORY_SCOPE_AGENT);
        __hip_atomic_store(stp + vtid + 256, rr[1], __ATOMIC_RELAXED, __HIP_MEMORY_SCOPE_AGENT);
    }
}

__global__ __launch_bounds__(512, 2)
void lstm_pipe(const float* __restrict__ x,
               const ushort_t* __restrict__ wf0, const ushort_t* __restrict__ wf1,
               const float* __restrict__ bp0, const float* __restrict__ bp1,
               uint32* __restrict__ h1k, float* __restrict__ lastH,
               uint32* __restrict__ flags)
{
    __shared__ ushort_t hb[4096];        // 8 KiB: h double buffer
    __shared__ ushort_t xb[4096];        // 8 KiB: x double buffer
    __shared__ float    accq[16384];     // 64 KiB: xacc quad double buffer
    const int blk = blockIdx.x;
    const int tid = threadIdx.x;
    ((uint32*)hb)[tid]       = 0u;       // zero h state (parity 0)
    ((uint32*)hb)[tid + 512] = 0u;
    if (blk < 64) {
        if (tid < 256) m_loop<6, true >(blk, wf0, nullptr, hb, accq);
        else           v_loop<6, true >(blk, x, nullptr, wf0, bp0, h1k,
                                        &flags[blk * 32], hb, xb, accq);
    } else {
        const int b = blk - 64;
        if (tid < 256) m_loop<8, false>(b, wf1, lastH, hb, accq);
        else           v_loop<8, false>(b, nullptr, h1k, wf1, bp1, nullptr,
                                        &flags[b * 32], hb, xb, accq);
    }
    __syncthreads();   // drain all waves' final stores
    if (blk < 64 && tid == 256)
        __hip_atomic_store(&flags[blk * 32], 1000u, __ATOMIC_RELEASE, __HIP_MEMORY_SCOPE_AGENT);
}

// ---------------- head: LayerNorm + fc1(relu) + fc2 ----------------
__global__ __launch_bounds__(256)
void head_kernel(const float* __restrict__ lastH,
                 const float* __restrict__ ln_g, const float* __restrict__ ln_b,
                 const float* __restrict__ fc1w, const float* __restrict__ fc1b,
                 const float* __restrict__ fc2w, const float* __restrict__ fc2b,
                 float* __restrict__ out) {
    __shared__ float ylds[4][128];
    int w = threadIdx.x >> 6, lane = threadIdx.x & 63;
    int row = blockIdx.x * 4 + w;
    float x0 = lastH[row * 128 + lane];
    float x1 = lastH[row * 128 + 64 + lane];
    float s = x0 + x1;
    for (int off = 32; off; off >>= 1) s += __shfl_xor(s, off);
    float mu = s * (1.f / 128.f);
    float d0 = x0 - mu, d1 = x1 - mu;
    float v = d0 * d0 + d1 * d1;
    for (int off = 32; off; off >>= 1) v += __shfl_xor(v, off);
    float rs = rsqrtf(v * (1.f / 128.f) + 1e-5f);
    ylds[w][lane]      = d0 * rs * ln_g[lane]      + ln_b[lane];
    ylds[w][lane + 64] = d1 * rs * ln_g[lane + 64] + ln_b[lane + 64];
    __syncthreads();
    float a = fc1b[lane];
#pragma unroll 4
    for (int k = 0; k < 128; ++k) a += ylds[w][k] * fc1w[lane * 128 + k];
    float r = fmaxf(a, 0.f) * fc2w[lane];
    for (int off = 32; off; off >>= 1) r += __shfl_xor(r, off);
    if (lane == 0) out[row] = r + fc2b[0];
}

extern "C" void kernel_launch(void* const* d_in, const int* in_sizes, int n_in,
                              void* d_out, int out_size, void* d_ws, size_t ws_size,
                              hipStream_t stream) {
    const float* x    = (const float*)d_in[0];
    const float* Wih0 = (const float*)d_in[1];
    const float* Whh0 = (const float*)d_in[2];
    const float* bih0 = (const float*)d_in[3];
    const float* bhh0 = (const float*)d_in[4];
    const float* Wih1 = (const float*)d_in[5];
    const float* Whh1 = (const float*)d_in[6];
    const float* bih1 = (const float*)d_in[7];
    const float* bhh1 = (const float*)d_in[8];
    const float* ln_g = (const float*)d_in[9];
    const float* ln_b = (const float*)d_in[10];
    const float* fc1w = (const float*)d_in[11];
    const float* fc1b = (const float*)d_in[12];
    const float* fc2w = (const float*)d_in[13];
    const float* fc2b = (const float*)d_in[14];

    char* ws = (char*)d_ws;
    uint32*   h1k   = (uint32*)  (ws);                 // 64 blk x 256 t x 4 KiB = 64 MiB
    ushort_t* wf0   = (ushort_t*)(ws + 67108864);      // 192 KiB
    ushort_t* wf1   = (ushort_t*)(ws + 67305472);      // 256 KiB
    float*    bp0   = (float*)   (ws + 67567616);      // 2 KiB
    float*    bp1   = (float*)   (ws + 67569664);      // 2 KiB
    float*    lastH = (float*)   (ws + 67571712);      // 512 KiB
    uint32*   flags = (uint32*)  (ws + 68096000);      // 8 KiB (64 flags, 128 B apart)

    prep_frag<0><<<384, 256, 0, stream>>>(Whh0, Wih0, wf0);
    prep_frag<1><<<512, 256, 0, stream>>>(Whh1, Wih1, wf1);
    prep_bias<<<4, 256, 0, stream>>>(bih0, bhh0, bih1, bhh1, bp0, bp1, flags);

    lstm_pipe<<<128, 512, 0, stream>>>(x, wf0, wf1, bp0, bp1, h1k, lastH, flags);

    head_kernel<<<256, 256, 0, stream>>>(lastH, ln_g, ln_b, fc1w, fc1b, fc2w, fc2b,
                                         (float*)d_out);
}